// Round 11
// baseline (3929.619 us; speedup 1.0000x reference)
//
#include <hip/hip_runtime.h>

// Round 11: R10 structure with TWO BATCH ROWS PER BLOCK in the rec kernels.
// R6/R10 post-mortems killed both latency micro-theories (prefetch age,
// barrier vmcnt drain). Remaining model: per-step serial chain (ds_read ->
// 28-deep FMA -> butterfly -> exp/rcp -> exp/rcp -> ds_write -> barrier)
// cannot be overlapped at 1.75 waves/SIMD. Fix: interleave two independent
// rows' chains on the same SIMDs (grid 128, block 2xHBLK; waves/CU 12.5/10/
// 6.5/4). Per-row code identical; barrier block-wide (rows lockstep).
// waves_per_eu cap dropped (would make 12.5-wave blocks unschedulable).

#define BATCH 256
#define TFULL 1024
#define TC    128
#define NCHUNK (TFULL / TC)

__device__ __forceinline__ float fast_rcp(float x) {
    return __builtin_amdgcn_rcpf(x);
}

// tanh(x) = sign(x) * (2/(1+e^{-2|x|}) - 1), via v_exp + v_rcp only.
__device__ __forceinline__ float tanh_fast(float x) {
    float e = __expf(-2.0f * fabsf(x));
    float r = fast_rcp(1.0f + e);
    return copysignf(fmaf(2.0f, r, -1.0f), x);
}

// LDS-only barrier: does NOT drain vmcnt.
__device__ __forceinline__ void lds_barrier() {
    asm volatile("s_waitcnt lgkmcnt(0)\n\ts_barrier" ::: "memory");
}

template<int CTRL>
__device__ __forceinline__ float dpp_add(float v) {
    int t = __builtin_amdgcn_update_dpp(0, __float_as_int(v), CTRL, 0xF, 0xF, true);
    return v + __int_as_float(t);
}
template<int CTRL>
__device__ __forceinline__ float dpp_mov(float v) {
    int t = __builtin_amdgcn_update_dpp(0, __float_as_int(v), CTRL, 0xF, 0xF, true);
    return __int_as_float(t);
}

// ---------------- Phase A: xg = x @ Wx + bias ----------------
template<int K, int N>
__global__ __launch_bounds__(256, 2)
void xg_gemm(const float* __restrict__ x, int batchStride,
             const float* __restrict__ Wx,    // [K, N]
             const float* __restrict__ bias,  // [N]
             float* __restrict__ out)
{
    constexpr int K4   = (K + 3) / 4;
    constexpr int SLAB = 64 * 4 + 4;

    const int n0   = blockIdx.x * 64;
    const int row0 = blockIdx.y * 64;
    const int tid  = threadIdx.x;
    const int tx   = tid & 15;
    const int ty   = tid >> 4;

    __shared__ __align__(16) float s_A[K4 * SLAB];
    __shared__ __align__(16) float s_B[K4 * 4 * 64];

    if constexpr ((K % 4) == 0) {
        for (int i = tid; i < 64 * (K / 4); i += 256) {
            const int row = i / (K / 4);
            const int k4  = i % (K / 4);
            const int gr  = row0 + row;
            const int b   = gr >> 7;
            const int t   = gr & 127;
            float4 v = *(const float4*)(x + (size_t)b * batchStride + t * K + k4 * 4);
            *(float4*)(s_A + k4 * SLAB + row * 4) = v;
        }
    } else {
        for (int i = tid; i < 64 * K; i += 256) {
            const int row = i / K;
            const int k   = i % K;
            const int gr  = row0 + row;
            const int b   = gr >> 7;
            const int t   = gr & 127;
            s_A[(k >> 2) * SLAB + row * 4 + (k & 3)] =
                x[(size_t)b * batchStride + t * K + k];
        }
        constexpr int PAD = K4 * 4 - K;
        for (int i = tid; i < 64 * PAD; i += 256) {
            const int row = i / PAD;
            const int kk  = K + i % PAD;
            s_A[(kk >> 2) * SLAB + row * 4 + (kk & 3)] = 0.0f;
        }
    }

    for (int i = tid; i < K4 * 4 * 16; i += 256) {
        const int k  = i >> 4;
        const int c4 = i & 15;
        float4 v = {0.0f, 0.0f, 0.0f, 0.0f};
        if (k < K && n0 + c4 * 4 < N)
            v = *(const float4*)(Wx + (size_t)k * N + n0 + c4 * 4);
        *(float4*)(s_B + k * 64 + c4 * 4) = v;
    }
    __syncthreads();

    float acc[4][4];
#pragma unroll
    for (int r = 0; r < 4; ++r)
#pragma unroll
        for (int c = 0; c < 4; ++c) acc[r][c] = 0.0f;

    for (int k4 = 0; k4 < K4; ++k4) {
        float4 bv[4];
#pragma unroll
        for (int j = 0; j < 4; ++j)
            bv[j] = *(const float4*)(s_B + (k4 * 4 + j) * 64 + tx * 4);
#pragma unroll
        for (int r = 0; r < 4; ++r) {
            float4 av = *(const float4*)(s_A + k4 * SLAB + (ty + 16 * r) * 4);
#pragma unroll
            for (int c = 0; c < 4; ++c) {
                acc[r][c] = fmaf(av.x, ((const float*)&bv[0])[c], acc[r][c]);
                acc[r][c] = fmaf(av.y, ((const float*)&bv[1])[c], acc[r][c]);
                acc[r][c] = fmaf(av.z, ((const float*)&bv[2])[c], acc[r][c]);
                acc[r][c] = fmaf(av.w, ((const float*)&bv[3])[c], acc[r][c]);
            }
        }
    }

    if (n0 + tx * 4 < N) {
        float4 bb = *(const float4*)(bias + n0 + tx * 4);
#pragma unroll
        for (int r = 0; r < 4; ++r) {
            float4 o;
            o.x = acc[r][0] + bb.x;
            o.y = acc[r][1] + bb.y;
            o.z = acc[r][2] + bb.z;
            o.w = acc[r][3] + bb.w;
            *(float4*)(out + (size_t)(row0 + ty + 16 * r) * N + n0 + tx * 4) = o;
        }
    }
}

// ---------------- Phase B: recurrence, TWO rows per block ----------------
// HBLK: per-row thread span (%4 == 0, >= 4U). BLOCK = 2*HBLK. Row =
// 2*blockIdx + (tid >= HBLK). 4 lanes/unit within a row; DPP quads never
// straddle the row boundary (HBLK % 4 == 0).
template<int U, int S, int HBLK, bool LAST>
__device__ __forceinline__ void rec_body(
    const float* __restrict__ xg,   // [B, TC, G]
    const float* __restrict__ Wh,   // [U, G]
    float* __restrict__ xout,       // [B, TC, U] (unless LAST)
    float* __restrict__ c_state,    // [B*U]
    float* __restrict__ h_state,    // [B*U]
    int first,
    const float* __restrict__ Wout, // [U] (LAST)
    const float* __restrict__ bout, // [1] (LAST)
    float* __restrict__ dout)       // [B] (LAST)
{
    constexpr int G     = 4 * U;
    constexpr int BLOCK = 2 * HBLK;

    const int tid  = threadIdx.x;
    const int half = (tid >= HBLK) ? 1 : 0;
    const int tin  = tid - half * HBLK;
    const int b    = blockIdx.x * 2 + half;
    const int u    = tin >> 2;
    const int s    = tin & 3;
    const bool act_th = (u < U);
    const int uu   = act_th ? u : 0;

    __shared__ __align__(16) float s_h[2][2][4 * S];   // [half][buf][...]

    float w4[4][S];
#pragma unroll
    for (int g = 0; g < 4; ++g)
#pragma unroll
        for (int kk = 0; kk < S; ++kk) {
            const int k = s * S + kk;
            w4[g][kk] = (act_th && k < U) ? Wh[(size_t)k * G + g * U + uu] : 0.0f;
        }

    for (int i = tid; i < 2 * 2 * 4 * S; i += BLOCK) ((float*)s_h)[i] = 0.0f;
    __syncthreads();
    if (tin < U) s_h[half][0][tin] = first ? 0.0f : h_state[b * U + tin];
    float c = first ? 0.0f : c_state[b * U + uu];
    __syncthreads();

    const float* xgp = xg + (size_t)b * TC * G + (s * U + uu);
    float xg0 = xgp[0];
    float xg1 = xgp[G];

    int cur = 0;
    float h = 0.0f, hprev = 0.0f;
    const bool is_t = (s == 2);

    for (int t = 0; t < TC; ++t, cur ^= 1) {
        // (1) t+2 prefetch
        const int tp = (t + 2 < TC) ? (t + 2) : (TC - 1);
        const float xg2 = xgp[(size_t)tp * G];

        // (2) deferred global store of last step's h
        if (!LAST) {
            if (act_th && s == 0 && t > 0)
                xout[((size_t)b * TC + (t - 1)) * U + u] = hprev;
        }

        // (3) partial dots over this lane's k-slice, all 4 gates
        float a0 = 0.0f, a1 = 0.0f, a2 = 0.0f, a3 = 0.0f;
        const float* hs = &s_h[half][cur][s * S];
#pragma unroll
        for (int kk = 0; kk < S; kk += 4) {
            float4 v = *(const float4*)(hs + kk);
            a0 = fmaf(v.x, w4[0][kk + 0], a0);
            a0 = fmaf(v.y, w4[0][kk + 1], a0);
            a0 = fmaf(v.z, w4[0][kk + 2], a0);
            a0 = fmaf(v.w, w4[0][kk + 3], a0);
            a1 = fmaf(v.x, w4[1][kk + 0], a1);
            a1 = fmaf(v.y, w4[1][kk + 1], a1);
            a1 = fmaf(v.z, w4[1][kk + 2], a1);
            a1 = fmaf(v.w, w4[1][kk + 3], a1);
            a2 = fmaf(v.x, w4[2][kk + 0], a2);
            a2 = fmaf(v.y, w4[2][kk + 1], a2);
            a2 = fmaf(v.z, w4[2][kk + 2], a2);
            a2 = fmaf(v.w, w4[2][kk + 3], a2);
            a3 = fmaf(v.x, w4[3][kk + 0], a3);
            a3 = fmaf(v.y, w4[3][kk + 1], a3);
            a3 = fmaf(v.z, w4[3][kk + 2], a3);
            a3 = fmaf(v.w, w4[3][kk + 3], a3);
        }

        // (4) quad butterfly
        a0 = dpp_add<0xB1>(a0); a0 = dpp_add<0x4E>(a0);
        a1 = dpp_add<0xB1>(a1); a1 = dpp_add<0x4E>(a1);
        a2 = dpp_add<0xB1>(a2); a2 = dpp_add<0x4E>(a2);
        a3 = dpp_add<0xB1>(a3); a3 = dpp_add<0x4E>(a3);

        // (5) lane s finalizes gate s (distributed activation)
        const float asum = (s == 0) ? a0 : (s == 1) ? a1 : (s == 2) ? a2 : a3;
        const float gs = asum + xg0;
        const float y  = is_t ? (-2.0f * fabsf(gs)) : (-gs);
        const float r  = fast_rcp(1.0f + __expf(y));
        const float v  = is_t ? copysignf(fmaf(2.0f, r, -1.0f), gs) : r;

        // (6) gather quad activations, update c/h (replicated)
        const float fi = dpp_mov<0x00>(v);
        const float ff = dpp_mov<0x55>(v);
        const float tc = dpp_mov<0xAA>(v);
        const float fo = dpp_mov<0xFF>(v);
        c = fmaf(ff, c, fi * tc);
        h = fo * tanh_fast(c);

        const int nxt = cur ^ 1;
        if (act_th && s == 0) s_h[half][nxt][u] = h;
        hprev = h;
        xg0 = xg1; xg1 = xg2;
        lds_barrier();
    }

    if (!LAST) {
        if (act_th && s == 0)
            xout[((size_t)b * TC + (TC - 1)) * U + u] = hprev;
    }
    if (act_th && s == 0) {
        c_state[b * U + u] = c;
        h_state[b * U + u] = h;
    }
    if (LAST && tin == 0) {
        float acc = bout[0];
#pragma unroll
        for (int k = 0; k < U; ++k) acc = fmaf(s_h[half][cur][k], Wout[k], acc);
        dout[b] = acc;
    }
}

#define REC_ARGS const float* __restrict__ xg, const float* __restrict__ Wh,        \
                 float* __restrict__ xout, float* __restrict__ c_state,             \
                 float* __restrict__ h_state, int first,                            \
                 const float* __restrict__ Wout, const float* __restrict__ bout,    \
                 float* __restrict__ dout
#define REC_PASS xg, Wh, xout, c_state, h_state, first, Wout, bout, dout

__attribute__((amdgpu_flat_work_group_size(800, 800)))
__global__ void rec_l0(REC_ARGS) { rec_body<100, 28, 400, false>(REC_PASS); }

__attribute__((amdgpu_flat_work_group_size(640, 640)))
__global__ void rec_l1(REC_ARGS) { rec_body<80, 20, 320, false>(REC_PASS); }

__attribute__((amdgpu_flat_work_group_size(416, 416)))
__global__ void rec_l2(REC_ARGS) { rec_body<50, 16, 208, false>(REC_PASS); }

__attribute__((amdgpu_flat_work_group_size(256, 256)))
__global__ void rec_l3(REC_ARGS) { rec_body<30, 8, 128, true>(REC_PASS); }

extern "C" void kernel_launch(void* const* d_in, const int* in_sizes, int n_in,
                              void* d_out, int out_size, void* d_ws, size_t ws_size,
                              hipStream_t stream)
{
    const float* seq  = (const float*)d_in[0];
    const float* Wx0  = (const float*)d_in[1];
    const float* Wh0  = (const float*)d_in[2];
    const float* b0   = (const float*)d_in[3];
    const float* Wx1  = (const float*)d_in[4];
    const float* Wh1  = (const float*)d_in[5];
    const float* b1   = (const float*)d_in[6];
    const float* Wx2  = (const float*)d_in[7];
    const float* Wh2  = (const float*)d_in[8];
    const float* b2   = (const float*)d_in[9];
    const float* Wx3  = (const float*)d_in[10];
    const float* Wh3  = (const float*)d_in[11];
    const float* b3   = (const float*)d_in[12];
    const float* Wout = (const float*)d_in[13];
    const float* bout = (const float*)d_in[14];
    float* out = (float*)d_out;

    const size_t XG_ELEMS = (size_t)BATCH * TC * 400;
    const size_t XC_ELEMS = (size_t)BATCH * TC * 100;
    float* ws  = (float*)d_ws;
    float* XGa = ws;
    float* XGb = XGa + XG_ELEMS;
    float* Xca = XGb + XG_ELEMS;
    float* Xcb = Xca + XC_ELEMS;
    float* st  = Xcb + XC_ELEMS;
    float* c0 = st + 0 * 32768; float* h0 = st + 1 * 32768;
    float* c1 = st + 2 * 32768; float* h1 = st + 3 * 32768;
    float* c2 = st + 4 * 32768; float* h2 = st + 5 * 32768;
    float* c3 = st + 6 * 32768; float* h3 = st + 7 * 32768;

    const dim3 gB(BATCH / 2);   // two rows per block

    for (int j = 0; j < NCHUNK; ++j) {
        const int first = (j == 0) ? 1 : 0;

        xg_gemm<64, 400><<<dim3(7, 512), 256, 0, stream>>>(
            seq + (size_t)j * TC * 64, TFULL * 64, Wx0, b0, XGa);
        rec_l0<<<gB, 800, 0, stream>>>(
            XGa, Wh0, Xca, c0, h0, first, nullptr, nullptr, nullptr);

        xg_gemm<100, 320><<<dim3(5, 512), 256, 0, stream>>>(
            Xca, TC * 100, Wx1, b1, XGb);
        rec_l1<<<gB, 640, 0, stream>>>(
            XGb, Wh1, Xcb, c1, h1, first, nullptr, nullptr, nullptr);

        xg_gemm<80, 200><<<dim3(4, 512), 256, 0, stream>>>(
            Xcb, TC * 80, Wx2, b2, XGa);
        rec_l2<<<gB, 416, 0, stream>>>(
            XGa, Wh2, Xca, c2, h2, first, nullptr, nullptr, nullptr);

        xg_gemm<50, 120><<<dim3(2, 512), 256, 0, stream>>>(
            Xca, TC * 50, Wx3, b3, XGb);
        rec_l3<<<gB, 256, 0, stream>>>(
            XGb, Wh3, nullptr, c3, h3, first, Wout, bout, out);
    }
}